// Round 1
// baseline (193.900 us; speedup 1.0000x reference)
//
#include <hip/hip_runtime.h>

// Problem constants
#define S_TOTAL 19648      // B*N sequential LSTM steps
#define T_CH    12         // chains (MFMA N dim, padded to 16)
#define HID     128
#define NT      512        // 8 waves per block

// R18: two interleaved chunk-chains per block. R14-R17 established the
// chunked-recurrence core and that 1 block/CU is a hardware fact; R17's
// counters (MfmaUtil 23%, VALUBusy 47%, step ~2870 cy vs ~1350 busy cy)
// show each step is latency-slack-bound, not throughput-bound. Two
// independent chains share the A-frags (W_hh, 80 VGPRs) and fill each
// other's stall cycles (m114: MFMA/VALU pipes co-schedule). 504 chunks
// of 39 outputs; block b runs chunks (2b, 2b+1): 71 steps vs 109.
#define CHUNK_L 39
#define NBLK    252        // ceil(19648/39)=504 chunks, 2 per block
#define WARMUP  32

typedef _Float16 half8  __attribute__((ext_vector_type(8)));
typedef _Float16 half4v __attribute__((ext_vector_type(4)));
typedef _Float16 half2v __attribute__((ext_vector_type(2)));
typedef float f4 __attribute__((ext_vector_type(4)));

#define NLOG2E  (-1.4426950408889634f)   // -log2(e): folded into i,f,o rows
#define N2LOG2E (-2.8853900817779268f)   // -2log2(e): folded into g rows

#if __has_builtin(__builtin_amdgcn_exp2f)
#define EXP2(x) __builtin_amdgcn_exp2f(x)
#else
#define EXP2(x) __expf((x) * 0.69314718055994531f)
#endif

__device__ __forceinline__ float sigz(float z) {   // z pre-scaled by -log2e
    return __builtin_amdgcn_rcpf(1.0f + EXP2(z));
}
__device__ __forceinline__ float tanz(float z) {   // z pre-scaled by -2log2e
    return __builtin_fmaf(2.0f, __builtin_amdgcn_rcpf(1.0f + EXP2(z)), -1.0f);
}
__device__ __forceinline__ float fdot2(half2v a, half2v b, float c) {
    return __builtin_amdgcn_fdot2(a, b, c, false);
}
#define MFMA(A, B, C) __builtin_amdgcn_mfma_f32_16x16x32_f16(A, B, C, 0, 0, 0)

__global__ __launch_bounds__(NT, 2) void lstm_fused(
    const float* __restrict__ x,      // (S,3,12): s*36 + f*12 + t
    const float* __restrict__ W_ih,   // (512,3)
    const float* __restrict__ W_hh,   // (512,128)
    const float* __restrict__ b_ih,   // (512)
    const float* __restrict__ b_hh,   // (512)
    const float* __restrict__ W_lin,  // (128)
    const float* __restrict__ b_lin,  // (1)
    float* __restrict__ out)          // (S,12): s*12 + t
{
    const int tid = threadIdx.x;
    const int w   = tid >> 6;    // wave 0..7 -> j-tile base 16w
    const int l   = tid & 63;
    const int n   = l & 15;      // chain col; for A, l&15 is row m
    const int qk  = l >> 4;      // k-quad / row-quad

    // Two chunks per block
    const int cA = 2 * blockIdx.x, cB = cA + 1;
    const int ostartA = cA * CHUNK_L, oendA = min(ostartA + CHUNK_L, S_TOTAL);
    const int ostartB = cB * CHUNK_L, oendB = min(ostartB + CHUNK_L, S_TOTAL);
    const int sbegA = max(0, ostartA - WARMUP);
    const int sbegB = max(0, ostartB - WARMUP);
    const int nstepsA = oendA - sbegA;
    const int nstepsB = oendB - sbegB;
    const int nsteps  = max(nstepsA, nstepsB);

    __shared__ __align__(16) _Float16 hfrag[2][2][5][64][8];   // [chain][p][kt][lane][e], 20480 B
    __shared__ __align__(16) float pout[2][2][16][8];          // [chain][p][col][wave], 2048 B

    // ---- A fragments (fp16, activation scales folded; SHARED by both chains) ----
    half8 A[4][5];
#pragma unroll
    for (int q = 0; q < 4; ++q) {
        const float sc = (q == 2) ? N2LOG2E : NLOG2E;
        const int row = q * HID + 16 * w + (l & 15);
#pragma unroll
        for (int kt = 0; kt < 4; ++kt) {
            const float* src = &W_hh[row * HID + kt * 32 + qk * 8];
            half8 a;
#pragma unroll
            for (int e = 0; e < 8; ++e) a[e] = (_Float16)(src[e] * sc);
            A[q][kt] = a;
        }
        half8 ae = {};
        if (qk == 0) {
            ae[0] = (_Float16)(W_ih[row * 3 + 0] * sc);
            ae[1] = (_Float16)(W_ih[row * 3 + 1] * sc);
            ae[2] = (_Float16)(W_ih[row * 3 + 2] * sc);
            ae[3] = (_Float16)((b_ih[row] + b_hh[row]) * sc);
        }
        A[q][4] = ae;
    }

    // W_lin pairs for this lane's 4 output rows j0..j0+3 (j0 = 16w + 4qk)
    const int j0 = 16 * w + 4 * qk;
    half2v wl01, wl23;
    wl01[0] = (_Float16)W_lin[j0];     wl01[1] = (_Float16)W_lin[j0 + 1];
    wl23[0] = (_Float16)W_lin[j0 + 2]; wl23[1] = (_Float16)W_lin[j0 + 3];
    const float blin = b_lin[0];

    // ---- zero LDS; seed bias + x(sbeg) for both chains ----
    uint4* hz = (uint4*)hfrag;
    hz[tid]       = make_uint4(0, 0, 0, 0);
    hz[tid + 512] = make_uint4(0, 0, 0, 0);
    if (tid < 256) hz[tid + 1024] = make_uint4(0, 0, 0, 0);
    __syncthreads();
    if (tid < 16) {
        hfrag[0][0][4][tid][3] = (_Float16)1.0f;
        hfrag[0][1][4][tid][3] = (_Float16)1.0f;
        hfrag[1][0][4][tid][3] = (_Float16)1.0f;
        hfrag[1][1][4][tid][3] = (_Float16)1.0f;
    }
    if (w == 0 && l < T_CH) {
        hfrag[0][0][4][l][0] = (_Float16)x[sbegA * 36 + l];
        hfrag[0][0][4][l][1] = (_Float16)x[sbegA * 36 + 12 + l];
        hfrag[0][0][4][l][2] = (_Float16)x[sbegA * 36 + 24 + l];
    }
    if (w == 1 && l < T_CH) {
        hfrag[1][0][4][l][0] = (_Float16)x[sbegB * 36 + l];
        hfrag[1][0][4][l][1] = (_Float16)x[sbegB * 36 + 12 + l];
        hfrag[1][0][4][l][2] = (_Float16)x[sbegB * 36 + 24 + l];
    }

    // ---- hoisted addresses ----
    const _Float16* rbA0 = &hfrag[0][0][0][l][0];
    const _Float16* rbA1 = &hfrag[0][1][0][l][0];
    const _Float16* rbB0 = &hfrag[1][0][0][l][0];
    const _Float16* rbB1 = &hfrag[1][1][0][l][0];
    const int ktw = w >> 1;
    const int lp  = (2 * (w & 1) + (qk >> 1)) * 16 + n;
    _Float16* wbA0 = &hfrag[0][0][ktw][lp][4 * (qk & 1)];
    _Float16* wbA1 = &hfrag[0][1][ktw][lp][4 * (qk & 1)];
    _Float16* wbB0 = &hfrag[1][0][ktw][lp][4 * (qk & 1)];
    _Float16* wbB1 = &hfrag[1][1][ktw][lp][4 * (qk & 1)];

    float cA0 = 0.f, cA1 = 0.f, cA2 = 0.f, cA3 = 0.f;
    float cB0 = 0.f, cB1 = 0.f, cB2 = 0.f, cB3 = 0.f;

    // x pipelines: wave 0 owns chain A, wave 1 owns chain B
    float xA1a = 0.f, xA1b = 0.f, xA1c = 0.f, xA2a = 0.f, xA2b = 0.f, xA2c = 0.f;
    float xB1a = 0.f, xB1b = 0.f, xB1c = 0.f, xB2a = 0.f, xB2b = 0.f, xB2c = 0.f;
    if (w == 0 && l < T_CH) {
        const int s1 = min(sbegA + 1, S_TOTAL - 1);
        const int s2 = min(sbegA + 2, S_TOTAL - 1);
        xA1a = x[s1 * 36 + l]; xA1b = x[s1 * 36 + 12 + l]; xA1c = x[s1 * 36 + 24 + l];
        xA2a = x[s2 * 36 + l]; xA2b = x[s2 * 36 + 12 + l]; xA2c = x[s2 * 36 + 24 + l];
    }
    if (w == 1 && l < T_CH) {
        const int s1 = min(sbegB + 1, S_TOTAL - 1);
        const int s2 = min(sbegB + 2, S_TOTAL - 1);
        xB1a = x[s1 * 36 + l]; xB1b = x[s1 * 36 + 12 + l]; xB1c = x[s1 * 36 + 24 + l];
        xB2a = x[s2 * 36 + l]; xB2b = x[s2 * 36 + 12 + l]; xB2c = x[s2 * 36 + 24 + l];
    }
    __syncthreads();

    auto step = [&](const int p, const int sA, const int sB) {
        const _Float16* ra = p ? rbA1 : rbA0;
        const _Float16* rb = p ? rbB1 : rbB0;

        // ---- B-frag ds_reads first, both chains (DS pipe starts) ----
        const half8 BA0 = *(const half8*)(ra + 0 * 512);
        const half8 BA1 = *(const half8*)(ra + 1 * 512);
        const half8 BA2 = *(const half8*)(ra + 2 * 512);
        const half8 BA3 = *(const half8*)(ra + 3 * 512);
        const half8 BA4 = *(const half8*)(ra + 4 * 512);
        const half8 BB0 = *(const half8*)(rb + 0 * 512);
        const half8 BB1 = *(const half8*)(rb + 1 * 512);
        const half8 BB2 = *(const half8*)(rb + 2 * 512);
        const half8 BB3 = *(const half8*)(rb + 3 * 512);
        const half8 BB4 = *(const half8*)(rb + 4 * 512);

        // ---- combine LAST step's partials: wave 7 chain A, wave 6 chain B ----
        if (w == 7 && l < T_CH && sA > ostartA && sA <= oendA) {
            const f4 pa = *(const f4*)&pout[0][p ^ 1][l][0];
            const f4 pb = *(const f4*)&pout[0][p ^ 1][l][4];
            out[(sA - 1) * T_CH + l] =
                pa.x + pa.y + pa.z + pa.w + pb.x + pb.y + pb.z + pb.w + blin;
        }
        if (w == 6 && l < T_CH && sB > ostartB && sB <= oendB) {
            const f4 pa = *(const f4*)&pout[1][p ^ 1][l][0];
            const f4 pb = *(const f4*)&pout[1][p ^ 1][l][4];
            out[(sB - 1) * T_CH + l] =
                pa.x + pa.y + pa.z + pa.w + pb.x + pb.y + pb.z + pb.w + blin;
        }

        // ---- publish x_{s+1} into ext tile of buffer p^1; rotate; load x_{s+3} ----
        if (w == 0 && l < T_CH) {
            _Float16* xd = p ? &hfrag[0][0][4][l][0] : &hfrag[0][1][4][l][0];
            half2v xp; xp[0] = (_Float16)xA1a; xp[1] = (_Float16)xA1b;
            *(half2v*)xd = xp;
            xd[2] = (_Float16)xA1c;
            xA1a = xA2a; xA1b = xA2b; xA1c = xA2c;
            const int sn = min(sA + 3, S_TOTAL - 1);
            xA2a = x[sn * 36 + l];
            xA2b = x[sn * 36 + 12 + l];
            xA2c = x[sn * 36 + 24 + l];
        }
        if (w == 1 && l < T_CH) {
            _Float16* xd = p ? &hfrag[1][0][4][l][0] : &hfrag[1][1][4][l][0];
            half2v xp; xp[0] = (_Float16)xB1a; xp[1] = (_Float16)xB1b;
            *(half2v*)xd = xp;
            xd[2] = (_Float16)xB1c;
            xB1a = xB2a; xB1b = xB2b; xB1c = xB2c;
            const int sn = min(sB + 3, S_TOTAL - 1);
            xB2a = x[sn * 36 + l];
            xB2b = x[sn * 36 + 12 + l];
            xB2c = x[sn * 36 + 24 + l];
        }

        // ---- MFMA: 8 independent depth-5 chains (4 gates x 2 chunks) ----
        const f4 z = {0.f, 0.f, 0.f, 0.f};
        f4 aA0 = MFMA(A[0][4], BA4, z), aB0 = MFMA(A[0][4], BB4, z);
        f4 aA1 = MFMA(A[1][4], BA4, z), aB1 = MFMA(A[1][4], BB4, z);
        f4 aA2 = MFMA(A[2][4], BA4, z), aB2 = MFMA(A[2][4], BB4, z);
        f4 aA3 = MFMA(A[3][4], BA4, z), aB3 = MFMA(A[3][4], BB4, z);
        aA0 = MFMA(A[0][0], BA0, aA0); aB0 = MFMA(A[0][0], BB0, aB0);
        aA1 = MFMA(A[1][0], BA0, aA1); aB1 = MFMA(A[1][0], BB0, aB1);
        aA2 = MFMA(A[2][0], BA0, aA2); aB2 = MFMA(A[2][0], BB0, aB2);
        aA3 = MFMA(A[3][0], BA0, aA3); aB3 = MFMA(A[3][0], BB0, aB3);
        aA0 = MFMA(A[0][1], BA1, aA0); aB0 = MFMA(A[0][1], BB1, aB0);
        aA1 = MFMA(A[1][1], BA1, aA1); aB1 = MFMA(A[1][1], BB1, aB1);
        aA2 = MFMA(A[2][1], BA1, aA2); aB2 = MFMA(A[2][1], BB1, aB2);
        aA3 = MFMA(A[3][1], BA1, aA3); aB3 = MFMA(A[3][1], BB1, aB3);
        aA0 = MFMA(A[0][2], BA2, aA0); aB0 = MFMA(A[0][2], BB2, aB0);
        aA1 = MFMA(A[1][2], BA2, aA1); aB1 = MFMA(A[1][2], BB2, aB1);
        aA2 = MFMA(A[2][2], BA2, aA2); aB2 = MFMA(A[2][2], BB2, aB2);
        aA3 = MFMA(A[3][2], BA2, aA3); aB3 = MFMA(A[3][2], BB2, aB3);
        aA0 = MFMA(A[0][3], BA3, aA0); aB0 = MFMA(A[0][3], BB3, aB0);
        aA1 = MFMA(A[1][3], BA3, aA1); aB1 = MFMA(A[1][3], BB3, aB1);
        aA2 = MFMA(A[2][3], BA3, aA2); aB2 = MFMA(A[2][3], BB3, aB2);
        aA3 = MFMA(A[3][3], BA3, aA3); aB3 = MFMA(A[3][3], BB3, aB3);

        // ---- gates chain A + c/h update ----
        float hA0, hA1, hA2, hA3;
        {
            const float i0 = sigz(aA0[0]), f0 = sigz(aA1[0]);
            const float g0 = tanz(aA2[0]), o0 = sigz(aA3[0]);
            cA0 = __builtin_fmaf(f0, cA0, i0 * g0);  hA0 = o0 * tanz(cA0 * N2LOG2E);
            const float i1 = sigz(aA0[1]), f1 = sigz(aA1[1]);
            const float g1 = tanz(aA2[1]), o1 = sigz(aA3[1]);
            cA1 = __builtin_fmaf(f1, cA1, i1 * g1);  hA1 = o1 * tanz(cA1 * N2LOG2E);
            const float i2 = sigz(aA0[2]), f2 = sigz(aA1[2]);
            const float g2 = tanz(aA2[2]), o2 = sigz(aA3[2]);
            cA2 = __builtin_fmaf(f2, cA2, i2 * g2);  hA2 = o2 * tanz(cA2 * N2LOG2E);
            const float i3 = sigz(aA0[3]), f3 = sigz(aA1[3]);
            const float g3 = tanz(aA2[3]), o3 = sigz(aA3[3]);
            cA3 = __builtin_fmaf(f3, cA3, i3 * g3);  hA3 = o3 * tanz(cA3 * N2LOG2E);
        }
        half4v hvA;
        hvA[0] = (_Float16)hA0; hvA[1] = (_Float16)hA1;
        hvA[2] = (_Float16)hA2; hvA[3] = (_Float16)hA3;
        *(half4v*)(p ? wbA0 : wbA1) = hvA;

        // ---- gates chain B + c/h update ----
        float hB0, hB1, hB2, hB3;
        {
            const float i0 = sigz(aB0[0]), f0 = sigz(aB1[0]);
            const float g0 = tanz(aB2[0]), o0 = sigz(aB3[0]);
            cB0 = __builtin_fmaf(f0, cB0, i0 * g0);  hB0 = o0 * tanz(cB0 * N2LOG2E);
            const float i1 = sigz(aB0[1]), f1 = sigz(aB1[1]);
            const float g1 = tanz(aB2[1]), o1 = sigz(aB3[1]);
            cB1 = __builtin_fmaf(f1, cB1, i1 * g1);  hB1 = o1 * tanz(cB1 * N2LOG2E);
            const float i2 = sigz(aB0[2]), f2 = sigz(aB1[2]);
            const float g2 = tanz(aB2[2]), o2 = sigz(aB3[2]);
            cB2 = __builtin_fmaf(f2, cB2, i2 * g2);  hB2 = o2 * tanz(cB2 * N2LOG2E);
            const float i3 = sigz(aB0[3]), f3 = sigz(aB1[3]);
            const float g3 = tanz(aB2[3]), o3 = sigz(aB3[3]);
            cB3 = __builtin_fmaf(f3, cB3, i3 * g3);  hB3 = o3 * tanz(cB3 * N2LOG2E);
        }
        half4v hvB;
        hvB[0] = (_Float16)hB0; hvB[1] = (_Float16)hB1;
        hvB[2] = (_Float16)hB2; hvB[3] = (_Float16)hB3;
        *(half4v*)(p ? wbB0 : wbB1) = hvB;

        // ---- pout partials (output-range steps only; uniform branches) ----
        if (sA >= ostartA && sA < oendA) {
            half2v h01, h23;
            h01[0] = hvA[0]; h01[1] = hvA[1];
            h23[0] = hvA[2]; h23[1] = hvA[3];
            float pp = fdot2(h23, wl23, fdot2(h01, wl01, 0.0f));
            pp += __shfl_xor(pp, 16, 64);
            pp += __shfl_xor(pp, 32, 64);
            if (qk == 0) pout[0][p][n][w] = pp;
        }
        if (sB >= ostartB && sB < oendB) {
            half2v h01, h23;
            h01[0] = hvB[0]; h01[1] = hvB[1];
            h23[0] = hvB[2]; h23[1] = hvB[3];
            float pp = fdot2(h23, wl23, fdot2(h01, wl01, 0.0f));
            pp += __shfl_xor(pp, 16, 64);
            pp += __shfl_xor(pp, 32, 64);
            if (qk == 0) pout[1][p][n][w] = pp;
        }
        __syncthreads();
    };

    int ss = 0;
    for (; ss + 2 <= nsteps; ss += 2) {
        step(0, sbegA + ss, sbegB + ss);
        step(1, sbegA + ss + 1, sbegB + ss + 1);
    }
    if (ss < nsteps) step(0, sbegA + ss, sbegB + ss);   // tail (ss even here)

    // ---- epilogue: final output for any chain whose last step was the last iter ----
    if (w == 7 && l < T_CH && nstepsA == nsteps) {
        const int pf = (nsteps - 1) & 1;
        const f4 pa = *(const f4*)&pout[0][pf][l][0];
        const f4 pb = *(const f4*)&pout[0][pf][l][4];
        out[(oendA - 1) * T_CH + l] =
            pa.x + pa.y + pa.z + pa.w + pb.x + pb.y + pb.z + pb.w + blin;
    }
    if (w == 6 && l < T_CH && nstepsB == nsteps) {
        const int pf = (nsteps - 1) & 1;
        const f4 pa = *(const f4*)&pout[1][pf][l][0];
        const f4 pb = *(const f4*)&pout[1][pf][l][4];
        out[(oendB - 1) * T_CH + l] =
            pa.x + pa.y + pa.z + pa.w + pb.x + pb.y + pb.z + pb.w + blin;
    }
}

extern "C" void kernel_launch(void* const* d_in, const int* in_sizes, int n_in,
                              void* d_out, int out_size, void* d_ws, size_t ws_size,
                              hipStream_t stream) {
    const float* x     = (const float*)d_in[0];
    const float* W_ih  = (const float*)d_in[1];
    const float* W_hh  = (const float*)d_in[2];
    const float* b_ih  = (const float*)d_in[3];
    const float* b_hh  = (const float*)d_in[4];
    const float* W_lin = (const float*)d_in[5];
    const float* b_lin = (const float*)d_in[6];
    float* out = (float*)d_out;

    hipLaunchKernelGGL(lstm_fused, dim3(NBLK), dim3(NT), 0, stream,
                       x, W_ih, W_hh, b_ih, b_hh, W_lin, b_lin, out);
}

// Round 2
// 188.487 us; speedup vs baseline: 1.0287x; 1.0287x over previous
//
#include <hip/hip_runtime.h>

// Problem constants
#define S_TOTAL 19648      // B*N sequential LSTM steps
#define T_CH    12         // chains (MFMA N dim, padded to 16)
#define HID     128
#define NT      512        // 8 waves per block

// R19: ANTI-PHASE two chunk-chains per block.
// R18 post-mortem: lockstep two-chain summed both phases serially
// (step 2870->5088 cy; VALU and MFMA busy cycles both doubled) -> the
// step is two serialized throughput phases (matrix ~640cy/SIMD, then
// VALU/trans gates ~860cy/SIMD), not latency slack. R19 staggers the
// chains: each slot = MFMA(chain X) + gates(chain Y), independent ->
// overlap on different pipes. Slot ~= max(pipes) + barrier edge.
// 504 chunks of 39 outputs, block b runs (2b, 2b+1); 2*71+1 slots.
// A-frags (80 regs) live in AGPRs (VGPR_Count 84 + 80 = ~164/wave ->
// 1 block/CU structural, R16).
#define CHUNK_L 39
#define NBLK    252        // ceil(19648/39)=504 chunks, 2 per block
#define WARMUP  32

typedef _Float16 half8  __attribute__((ext_vector_type(8)));
typedef _Float16 half4v __attribute__((ext_vector_type(4)));
typedef _Float16 half2v __attribute__((ext_vector_type(2)));
typedef float f4 __attribute__((ext_vector_type(4)));

#define NLOG2E  (-1.4426950408889634f)   // -log2(e): folded into i,f,o rows
#define N2LOG2E (-2.8853900817779268f)   // -2log2(e): folded into g rows

#if __has_builtin(__builtin_amdgcn_exp2f)
#define EXP2(x) __builtin_amdgcn_exp2f(x)
#else
#define EXP2(x) __expf((x) * 0.69314718055994531f)
#endif

__device__ __forceinline__ float sigz(float z) {   // z pre-scaled by -log2e
    return __builtin_amdgcn_rcpf(1.0f + EXP2(z));
}
__device__ __forceinline__ float tanz(float z) {   // z pre-scaled by -2log2e
    return __builtin_fmaf(2.0f, __builtin_amdgcn_rcpf(1.0f + EXP2(z)), -1.0f);
}
__device__ __forceinline__ float fdot2(half2v a, half2v b, float c) {
    return __builtin_amdgcn_fdot2(a, b, c, false);
}
#define MFMA(A, B, C) __builtin_amdgcn_mfma_f32_16x16x32_f16(A, B, C, 0, 0, 0)

// ---- slot-phase macros -------------------------------------------------
// B-frag loads for the MFMA-phase chain (issued first: ds latency hides
// under the other chain's gate VALU).
#define LOADS(CIDX)                                                      \
    {                                                                    \
        const _Float16* rbp = &hfrag[CIDX][0][l][0];                     \
        Bf0 = *(const half8*)(rbp + 0 * 512);                            \
        Bf1 = *(const half8*)(rbp + 1 * 512);                            \
        Bf2 = *(const half8*)(rbp + 2 * 512);                            \
        Bf3 = *(const half8*)(rbp + 3 * 512);                            \
        Bf4 = *(const half8*)(rbp + 4 * 512);                            \
    }

// 20 MFMAs for chain X; depth-5 accumulation per gate (R18-verified
// ordering -> absmax bit-compatible). Results consumed one slot later.
#define MFMAS(X)                                                         \
    {                                                                    \
        const f4 z = {0.f, 0.f, 0.f, 0.f};                               \
        a##X##0 = MFMA(A[0][4], Bf4, z);                                 \
        a##X##1 = MFMA(A[1][4], Bf4, z);                                 \
        a##X##2 = MFMA(A[2][4], Bf4, z);                                 \
        a##X##3 = MFMA(A[3][4], Bf4, z);                                 \
        a##X##0 = MFMA(A[0][0], Bf0, a##X##0);                           \
        a##X##1 = MFMA(A[1][0], Bf0, a##X##1);                           \
        a##X##2 = MFMA(A[2][0], Bf0, a##X##2);                           \
        a##X##3 = MFMA(A[3][0], Bf0, a##X##3);                           \
        a##X##0 = MFMA(A[0][1], Bf1, a##X##0);                           \
        a##X##1 = MFMA(A[1][1], Bf1, a##X##1);                           \
        a##X##2 = MFMA(A[2][1], Bf1, a##X##2);                           \
        a##X##3 = MFMA(A[3][1], Bf1, a##X##3);                           \
        a##X##0 = MFMA(A[0][2], Bf2, a##X##0);                           \
        a##X##1 = MFMA(A[1][2], Bf2, a##X##1);                           \
        a##X##2 = MFMA(A[2][2], Bf2, a##X##2);                           \
        a##X##3 = MFMA(A[3][2], Bf2, a##X##3);                           \
        a##X##0 = MFMA(A[0][3], Bf3, a##X##0);                           \
        a##X##1 = MFMA(A[1][3], Bf3, a##X##1);                           \
        a##X##2 = MFMA(A[2][3], Bf3, a##X##2);                           \
        a##X##3 = MFMA(A[3][3], Bf3, a##X##3);                           \
    }

// Full gate phase for chain X at step index jv: out-combine for the
// previous step, x publish+prefetch, gate nonlinearities + c/h update,
// h publish to LDS, W_lin partials. All external side effects are
// range-guarded, so chains may harmlessly overrun their nsteps.
#define GATES(X, CIDX, WOUT, WXP, jv)                                    \
    {                                                                    \
        const int sX = sbeg##X + (jv);                                   \
        const int pj = (jv) & 1;                                         \
        if (w == (WOUT) && l < T_CH && sX > ostart##X && sX <= oend##X) {\
            const f4 pa = *(const f4*)&pout[CIDX][pj ^ 1][l][0];         \
            const f4 pb = *(const f4*)&pout[CIDX][pj ^ 1][l][4];         \
            out[(sX - 1) * T_CH + l] = pa.x + pa.y + pa.z + pa.w         \
                + pb.x + pb.y + pb.z + pb.w + blin;                      \
        }                                                                \
        if (w == (WXP) && l < T_CH) {                                    \
            _Float16* xd = &hfrag[CIDX][4][l][0];                        \
            half2v xp; xp[0] = (_Float16)x##X##1a;                       \
            xp[1] = (_Float16)x##X##1b;                                  \
            *(half2v*)xd = xp;                                           \
            xd[2] = (_Float16)x##X##1c;                                  \
            x##X##1a = x##X##2a; x##X##1b = x##X##2b;                    \
            x##X##1c = x##X##2c;                                         \
            const int sn = min(sX + 3, S_TOTAL - 1);                     \
            x##X##2a = x[sn * 36 + l];                                   \
            x##X##2b = x[sn * 36 + 12 + l];                              \
            x##X##2c = x[sn * 36 + 24 + l];                              \
        }                                                                \
        const float i0 = sigz(a##X##0[0]), f0 = sigz(a##X##1[0]);        \
        const float g0 = tanz(a##X##2[0]), o0 = sigz(a##X##3[0]);        \
        c##X##0 = __builtin_fmaf(f0, c##X##0, i0 * g0);                  \
        const float h0 = o0 * tanz(c##X##0 * N2LOG2E);                   \
        const float i1 = sigz(a##X##0[1]), f1 = sigz(a##X##1[1]);        \
        const float g1 = tanz(a##X##2[1]), o1 = sigz(a##X##3[1]);        \
        c##X##1 = __builtin_fmaf(f1, c##X##1, i1 * g1);                  \
        const float h1 = o1 * tanz(c##X##1 * N2LOG2E);                   \
        const float i2 = sigz(a##X##0[2]), f2 = sigz(a##X##1[2]);        \
        const float g2 = tanz(a##X##2[2]), o2 = sigz(a##X##3[2]);        \
        c##X##2 = __builtin_fmaf(f2, c##X##2, i2 * g2);                  \
        const float h2 = o2 * tanz(c##X##2 * N2LOG2E);                   \
        const float i3 = sigz(a##X##0[3]), f3 = sigz(a##X##1[3]);        \
        const float g3 = tanz(a##X##2[3]), o3 = sigz(a##X##3[3]);        \
        c##X##3 = __builtin_fmaf(f3, c##X##3, i3 * g3);                  \
        const float h3 = o3 * tanz(c##X##3 * N2LOG2E);                   \
        half4v hv;                                                       \
        hv[0] = (_Float16)h0; hv[1] = (_Float16)h1;                      \
        hv[2] = (_Float16)h2; hv[3] = (_Float16)h3;                      \
        *(half4v*)wb##X = hv;                                            \
        if (sX >= ostart##X && sX < oend##X) {                           \
            half2v h01, h23;                                             \
            h01[0] = hv[0]; h01[1] = hv[1];                              \
            h23[0] = hv[2]; h23[1] = hv[3];                              \
            float pp = fdot2(h23, wl23, fdot2(h01, wl01, 0.0f));         \
            pp += __shfl_xor(pp, 16, 64);                                \
            pp += __shfl_xor(pp, 32, 64);                                \
            if (qk == 0) pout[CIDX][pj][n][w] = pp;                      \
        }                                                                \
    }

__global__ __launch_bounds__(NT, 2) void lstm_fused(
    const float* __restrict__ x,      // (S,3,12): s*36 + f*12 + t
    const float* __restrict__ W_ih,   // (512,3)
    const float* __restrict__ W_hh,   // (512,128)
    const float* __restrict__ b_ih,   // (512)
    const float* __restrict__ b_hh,   // (512)
    const float* __restrict__ W_lin,  // (128)
    const float* __restrict__ b_lin,  // (1)
    float* __restrict__ out)          // (S,12): s*12 + t
{
    const int tid = threadIdx.x;
    const int w   = tid >> 6;    // wave 0..7 -> j-tile base 16w
    const int l   = tid & 63;
    const int n   = l & 15;      // chain col; for A, l&15 is row m
    const int qk  = l >> 4;      // k-quad / row-quad

    // Two chunks per block
    const int cA = 2 * blockIdx.x, cB = cA + 1;
    const int ostartA = cA * CHUNK_L, oendA = min(ostartA + CHUNK_L, S_TOTAL);
    const int ostartB = cB * CHUNK_L, oendB = min(ostartB + CHUNK_L, S_TOTAL);
    const int sbegA = max(0, ostartA - WARMUP);
    const int sbegB = max(0, ostartB - WARMUP);
    const int nstepsA = oendA - sbegA;
    const int nstepsB = oendB - sbegB;
    const int nsteps  = max(nstepsA, nstepsB);

    // Single-buffered h per chain: writer (gates, slot k) and reader
    // (MFMA, slots k-1 / k+1) are barrier-separated by construction.
    __shared__ __align__(16) _Float16 hfrag[2][5][64][8];   // 10240 B
    __shared__ __align__(16) float pout[2][2][16][8];       // 2048 B

    // ---- A fragments (fp16, activation scales folded; shared) ----
    half8 A[4][5];
#pragma unroll
    for (int q = 0; q < 4; ++q) {
        const float sc = (q == 2) ? N2LOG2E : NLOG2E;
        const int row = q * HID + 16 * w + (l & 15);
#pragma unroll
        for (int kt = 0; kt < 4; ++kt) {
            const float* src = &W_hh[row * HID + kt * 32 + qk * 8];
            half8 a;
#pragma unroll
            for (int e = 0; e < 8; ++e) a[e] = (_Float16)(src[e] * sc);
            A[q][kt] = a;
        }
        half8 ae = {};
        if (qk == 0) {
            ae[0] = (_Float16)(W_ih[row * 3 + 0] * sc);
            ae[1] = (_Float16)(W_ih[row * 3 + 1] * sc);
            ae[2] = (_Float16)(W_ih[row * 3 + 2] * sc);
            ae[3] = (_Float16)((b_ih[row] + b_hh[row]) * sc);
        }
        A[q][4] = ae;
    }

    // W_lin pairs for this lane's 4 output rows j0..j0+3 (j0 = 16w + 4qk)
    const int j0 = 16 * w + 4 * qk;
    half2v wl01, wl23;
    wl01[0] = (_Float16)W_lin[j0];     wl01[1] = (_Float16)W_lin[j0 + 1];
    wl23[0] = (_Float16)W_lin[j0 + 2]; wl23[1] = (_Float16)W_lin[j0 + 3];
    const float blin = b_lin[0];

    // ---- zero LDS; seed bias + x(sbeg) for both chains ----
    uint4* hz = (uint4*)hfrag;
    hz[tid] = make_uint4(0, 0, 0, 0);
    if (tid < 128) hz[512 + tid] = make_uint4(0, 0, 0, 0);
    __syncthreads();
    if (tid < 16) {
        hfrag[0][4][tid][3] = (_Float16)1.0f;
        hfrag[1][4][tid][3] = (_Float16)1.0f;
    }
    if (w == 0 && l < T_CH) {
        hfrag[0][4][l][0] = (_Float16)x[sbegA * 36 + l];
        hfrag[0][4][l][1] = (_Float16)x[sbegA * 36 + 12 + l];
        hfrag[0][4][l][2] = (_Float16)x[sbegA * 36 + 24 + l];
    }
    if (w == 1 && l < T_CH) {
        hfrag[1][4][l][0] = (_Float16)x[sbegB * 36 + l];
        hfrag[1][4][l][1] = (_Float16)x[sbegB * 36 + 12 + l];
        hfrag[1][4][l][2] = (_Float16)x[sbegB * 36 + 24 + l];
    }

    // ---- hoisted h-write addresses ----
    const int ktw = w >> 1;
    const int lp  = (2 * (w & 1) + (qk >> 1)) * 16 + n;
    _Float16* wbA = &hfrag[0][ktw][lp][4 * (qk & 1)];
    _Float16* wbB = &hfrag[1][ktw][lp][4 * (qk & 1)];

    // ---- persistent per-chain state ----
    f4 aA0 = {0.f,0.f,0.f,0.f}, aA1 = aA0, aA2 = aA0, aA3 = aA0;
    f4 aB0 = aA0, aB1 = aA0, aB2 = aA0, aB3 = aA0;
    float cA0 = 0.f, cA1 = 0.f, cA2 = 0.f, cA3 = 0.f;
    float cB0 = 0.f, cB1 = 0.f, cB2 = 0.f, cB3 = 0.f;

    // x pipelines: wave 0 owns chain A, wave 1 owns chain B
    float xA1a = 0.f, xA1b = 0.f, xA1c = 0.f, xA2a = 0.f, xA2b = 0.f, xA2c = 0.f;
    float xB1a = 0.f, xB1b = 0.f, xB1c = 0.f, xB2a = 0.f, xB2b = 0.f, xB2c = 0.f;
    if (w == 0 && l < T_CH) {
        const int s1 = min(sbegA + 1, S_TOTAL - 1);
        const int s2 = min(sbegA + 2, S_TOTAL - 1);
        xA1a = x[s1 * 36 + l]; xA1b = x[s1 * 36 + 12 + l]; xA1c = x[s1 * 36 + 24 + l];
        xA2a = x[s2 * 36 + l]; xA2b = x[s2 * 36 + 12 + l]; xA2c = x[s2 * 36 + 24 + l];
    }
    if (w == 1 && l < T_CH) {
        const int s1 = min(sbegB + 1, S_TOTAL - 1);
        const int s2 = min(sbegB + 2, S_TOTAL - 1);
        xB1a = x[s1 * 36 + l]; xB1b = x[s1 * 36 + 12 + l]; xB1c = x[s1 * 36 + 24 + l];
        xB2a = x[s2 * 36 + l]; xB2b = x[s2 * 36 + 12 + l]; xB2c = x[s2 * 36 + 24 + l];
    }
    __syncthreads();

    // ---- prologue slot 0: MFMA_A(0) ----
    {
        half8 Bf0, Bf1, Bf2, Bf3, Bf4;
        LOADS(0);
        MFMAS(A);
    }
    __syncthreads();

    // ---- main anti-phase loop: 2 slots per iteration ----
    for (int i = 0; i < nsteps; ++i) {
        {   // odd slot 2i+1: MFMA_B(i) overlaps gates_A(i)
            half8 Bf0, Bf1, Bf2, Bf3, Bf4;
            LOADS(1);
            GATES(A, 0, 7, 0, i);
            MFMAS(B);
        }
        __syncthreads();
        {   // even slot 2i+2: MFMA_A(i+1) overlaps gates_B(i)
            half8 Bf0, Bf1, Bf2, Bf3, Bf4;
            LOADS(0);
            GATES(B, 1, 6, 1, i);
            MFMAS(A);
        }
        __syncthreads();
    }

    // ---- epilogue: final output for chains that did not overrun ----
    // (chains with nstepsX < nsteps already combined their final output
    //  in-loop at j = nstepsX via the sX <= oendX guard)
    if (w == 7 && l < T_CH && nstepsA == nsteps) {
        const int pf = (nstepsA - 1) & 1;
        const f4 pa = *(const f4*)&pout[0][pf][l][0];
        const f4 pb = *(const f4*)&pout[0][pf][l][4];
        out[(oendA - 1) * T_CH + l] =
            pa.x + pa.y + pa.z + pa.w + pb.x + pb.y + pb.z + pb.w + blin;
    }
    if (w == 6 && l < T_CH && nstepsB == nsteps) {
        const int pf = (nstepsB - 1) & 1;
        const f4 pa = *(const f4*)&pout[1][pf][l][0];
        const f4 pb = *(const f4*)&pout[1][pf][l][4];
        out[(oendB - 1) * T_CH + l] =
            pa.x + pa.y + pa.z + pa.w + pb.x + pb.y + pb.z + pb.w + blin;
    }
}

extern "C" void kernel_launch(void* const* d_in, const int* in_sizes, int n_in,
                              void* d_out, int out_size, void* d_ws, size_t ws_size,
                              hipStream_t stream) {
    const float* x     = (const float*)d_in[0];
    const float* W_ih  = (const float*)d_in[1];
    const float* W_hh  = (const float*)d_in[2];
    const float* b_ih  = (const float*)d_in[3];
    const float* b_hh  = (const float*)d_in[4];
    const float* W_lin = (const float*)d_in[5];
    const float* b_lin = (const float*)d_in[6];
    float* out = (float*)d_out;

    hipLaunchKernelGGL(lstm_fused, dim3(NBLK), dim3(NT), 0, stream,
                       x, W_ih, W_hh, b_ih, b_hh, W_lin, b_lin, out);
}